// Round 14
// baseline (496.896 us; speedup 1.0000x reference)
//
#include <hip/hip_runtime.h>
#include <hip/hip_bf16.h>

// ---------- types ----------
typedef short bf16x8 __attribute__((ext_vector_type(8)));   // 8 bf16 (4 VGPRs)
typedef float f32x4  __attribute__((ext_vector_type(4)));

typedef __attribute__((address_space(1))) const unsigned int gu32_t;
typedef __attribute__((address_space(3))) unsigned int lu32_t;

__device__ inline void gld16(const void* g, void* l) {
  // async global->LDS, 16B per lane; dest must be wave-uniform-base + lane*16
  __builtin_amdgcn_global_load_lds((gu32_t*)g, (lu32_t*)l, 16, 0, 0);
}

__device__ inline float bf2f(__hip_bfloat16 x) { return __bfloat162float(x); }

#define S_LEN 2048
#define HID   4096
#define NH    32
#define HD    128
#define QKV_N 12288

// ---------- fp32 -> bf16 convert (vectorized, grid-stride) ----------
__global__ void cvt_bf16_kernel(const float* __restrict__ in,
                                __hip_bfloat16* __restrict__ out, long n) {
  long stride = (long)gridDim.x * blockDim.x;
  for (long i = (long)blockIdx.x * blockDim.x + threadIdx.x; i * 8 < n; i += stride) {
    long b = i * 8;
    float4 a0 = *(const float4*)(in + b);
    float4 a1 = *(const float4*)(in + b + 4);
    union { __hip_bfloat16 h[8]; bf16x8 v; } u;
    u.h[0] = __float2bfloat16(a0.x); u.h[1] = __float2bfloat16(a0.y);
    u.h[2] = __float2bfloat16(a0.z); u.h[3] = __float2bfloat16(a0.w);
    u.h[4] = __float2bfloat16(a1.x); u.h[5] = __float2bfloat16(a1.y);
    u.h[6] = __float2bfloat16(a1.z); u.h[7] = __float2bfloat16(a1.w);
    *(bf16x8*)(out + b) = u.v;
  }
}

// ---------- GEMM (m97 structure, 900 TF = structural ceiling here) ----------
// T1 XCD chunk swizzle (FETCH 420->200MB, R13) + T2 LDS swizzle (R5).
// Compute-bound at MfmaUtil 42 + VALUBusy 49; frozen.
template<int WRITE_BF16>
__global__ __launch_bounds__(256) void gemm_bt_kernel(
    const __hip_bfloat16* __restrict__ A,
    const __hip_bfloat16* __restrict__ B,
    const float* __restrict__ bias,
    void* __restrict__ Cout, int M, int N, int K)
{
  __shared__ __hip_bfloat16 lA[128 * 64];
  __shared__ __hip_bfloat16 lB[128 * 64];
  const int t = threadIdx.x;
  const int w = t >> 6, l = t & 63;
  const int lr = l & 15, lg = l >> 4;
  const int nwg = gridDim.x * gridDim.y;
  const int bid = blockIdx.y * gridDim.x + blockIdx.x;
  const int swz = (bid & 7) * (nwg >> 3) + (bid >> 3);   // XCD chunk swizzle
  const int m0 = (swz % gridDim.x) * 128, n0 = (swz / gridDim.x) * 128;
  const int wm = (w >> 1) * 64, wn = (w & 1) * 64;

  f32x4 acc[4][4] = {};

  for (int k0 = 0; k0 < K; k0 += 64) {
    #pragma unroll
    for (int i = 0; i < 4; ++i) {
      int c = i * 256 + t;            // chunk id 0..1023, 16B each, linear in LDS
      int row = c >> 3, s = c & 7;    // source slot pre-swizzled: s ^ (row&7)
      gld16(A + (long)(m0 + row) * K + k0 + (s ^ (row & 7)) * 8, &lA[c * 8]);
    }
    #pragma unroll
    for (int i = 0; i < 4; ++i) {
      int c = i * 256 + t;
      int row = c >> 3, s = c & 7;
      gld16(B + (long)(n0 + row) * K + k0 + (s ^ (row & 7)) * 8, &lB[c * 8]);
    }
    __syncthreads();                  // drains vmcnt before barrier
    #pragma unroll
    for (int ks = 0; ks < 2; ++ks) {
      bf16x8 af[4], bfr[4];
      #pragma unroll
      for (int mi = 0; mi < 4; ++mi) {
        int row = wm + mi * 16 + lr;
        af[mi] = *(const bf16x8*)&lA[row * 64 + ((ks * 4 + lg) ^ (row & 7)) * 8];
      }
      #pragma unroll
      for (int ni = 0; ni < 4; ++ni) {
        int row = wn + ni * 16 + lr;
        bfr[ni] = *(const bf16x8*)&lB[row * 64 + ((ks * 4 + lg) ^ (row & 7)) * 8];
      }
      #pragma unroll
      for (int mi = 0; mi < 4; ++mi)
        #pragma unroll
        for (int ni = 0; ni < 4; ++ni)
          acc[mi][ni] = __builtin_amdgcn_mfma_f32_16x16x32_bf16(af[mi], bfr[ni], acc[mi][ni], 0, 0, 0);
    }
    __syncthreads();
  }

  #pragma unroll
  for (int mi = 0; mi < 4; ++mi) {
    #pragma unroll
    for (int ni = 0; ni < 4; ++ni) {
      int col = n0 + wn + ni * 16 + lr;
      float bv = bias[col];
      #pragma unroll
      for (int r = 0; r < 4; ++r) {
        int row = m0 + wm + mi * 16 + lg * 4 + r;     // C/D: col=lane&15, row=(lane>>4)*4+reg
        float v = acc[mi][ni][r] + bv;
        if (WRITE_BF16)
          ((__hip_bfloat16*)Cout)[(long)row * N + col] = __float2bfloat16(v);
        else
          ((float*)Cout)[(long)row * N + col] = v;
      }
    }
  }
}

// ---------- RoPE cos/sin table: [s][64] ----------
__global__ void rope_table_kernel(const int* __restrict__ pos,
                                  float* __restrict__ ct, float* __restrict__ st) {
  int s = blockIdx.x, j = threadIdx.x;      // 2048 x 64
  float p = (float)pos[s];
  float invf = exp2f(-0.20762050593046013f * (float)j);
  float a = p * invf;
  ct[s * 64 + j] = cosf(a);
  st[s * 64 + j] = sinf(a);
}

// ---------- RoPE + rearrange (vectorized, R13) ----------
__global__ __launch_bounds__(256) void rope_rearrange_kernel(
    const __hip_bfloat16* __restrict__ qkv,
    const float* __restrict__ ct, const float* __restrict__ st,
    __hip_bfloat16* __restrict__ Qr, __hip_bfloat16* __restrict__ Kr,
    __hip_bfloat16* __restrict__ Vt)
{
  __shared__ __hip_bfloat16 lv[64][136];    // padded to break bank conflicts on transpose read
  const int h = blockIdx.y, s0 = blockIdx.x * 64, t = threadIdx.x;

  #pragma unroll
  for (int half = 0; half < 2; ++half) {
    int si = half * 32 + (t >> 3);          // row within tile
    int jo = (t & 7) * 8;                   // 8 consecutive j per lane
    long base = (long)(s0 + si) * QKV_N + h * 384;
    union { __hip_bfloat16 h8[8]; bf16x8 v; } q1, q2, k1, k2, o;
    q1.v = *(const bf16x8*)(qkv + base + jo);
    q2.v = *(const bf16x8*)(qkv + base + 64 + jo);
    k1.v = *(const bf16x8*)(qkv + base + 128 + jo);
    k2.v = *(const bf16x8*)(qkv + base + 192 + jo);
    const float* cp = ct + (s0 + si) * 64 + jo;
    const float* sp = st + (s0 + si) * 64 + jo;
    long ob = (long)h * (S_LEN * HD) + (long)(s0 + si) * HD;
    #pragma unroll
    for (int e = 0; e < 8; ++e)
      o.h8[e] = __float2bfloat16(bf2f(q1.h8[e]) * cp[e] - bf2f(q2.h8[e]) * sp[e]);
    *(bf16x8*)(Qr + ob + jo) = o.v;
    #pragma unroll
    for (int e = 0; e < 8; ++e)
      o.h8[e] = __float2bfloat16(bf2f(q2.h8[e]) * cp[e] + bf2f(q1.h8[e]) * sp[e]);
    *(bf16x8*)(Qr + ob + 64 + jo) = o.v;
    #pragma unroll
    for (int e = 0; e < 8; ++e)
      o.h8[e] = __float2bfloat16(bf2f(k1.h8[e]) * cp[e] - bf2f(k2.h8[e]) * sp[e]);
    *(bf16x8*)(Kr + ob + jo) = o.v;
    #pragma unroll
    for (int e = 0; e < 8; ++e)
      o.h8[e] = __float2bfloat16(bf2f(k2.h8[e]) * cp[e] + bf2f(k1.h8[e]) * sp[e]);
    *(bf16x8*)(Kr + ob + 64 + jo) = o.v;
    *(bf16x8*)&lv[si][jo]      = *(const bf16x8*)(qkv + base + 256 + jo);
    *(bf16x8*)&lv[si][64 + jo] = *(const bf16x8*)(qkv + base + 320 + jo);
  }
  __syncthreads();
  #pragma unroll
  for (int i = 0; i < 4; ++i) {
    int c = i * 256 + t;                    // 128 d x 8 chunks of 8 s
    int d = c >> 3, s8 = (c & 7) * 8;
    union { __hip_bfloat16 h8[8]; bf16x8 v; } u;
    #pragma unroll
    for (int j2 = 0; j2 < 8; ++j2) u.h8[j2] = lv[s8 + j2][d];
    *(bf16x8*)(Vt + (long)h * (HD * S_LEN) + (long)d * S_LEN + s0 + s8) = u.v;
  }
}

// ---------- causal flash attention: QBLK=128, 32 q-rows per wave ----------
// ROUND 14 (one lever): the kernel was LDS-read-throughput-bound — all 4
// waves re-read the same lK/lV tiles for only 16 q-rows each (~137KB LDS
// reads per block-k-tile vs 154 cyc MFMA). Doubling q-rows/wave to 32
// (2 m-frags, mi dimension) halves LDS bytes AND barriers per FLOP: each
// kf feeds 2 QK-MFMAs, each vf feeds 2 PV-MFMAs.
// Causal pairing at QBLK=128: q-tile qt needs 2qt+2 k-tiles; block p does
// {p, 15-p} -> 34 k-tiles uniform. Grid 8x32 = 256 blocks (1/CU, no tail).
// K/V double-buffered (overlap stage with compute); R12 softmax: log2
// domain, diagonal-only mask (kt >= 2qt), T13 defer-max THR=8.
// lK: 16 slots/row swizzle row&15; lV: 8 slots/row swizzle row&7 (T2).
#define FA_STAGE(buf, k0_) do {                                              \
    _Pragma("unroll")                                                        \
    for (int i_ = 0; i_ < 4; ++i_) {       /* K tile: 64 k x 128 d */        \
      int c_ = i_ * 256 + t;                                                 \
      int row_ = c_ >> 4, s_ = c_ & 15;                                      \
      gld16(Kh + (long)((k0_) + row_) * HD + (s_ ^ (row_ & 15)) * 8,         \
            &lK[buf][c_ * 8]);                                               \
    }                                                                        \
    _Pragma("unroll")                                                        \
    for (int i_ = 0; i_ < 4; ++i_) {       /* V^T tile: 128 d x 64 k */      \
      int c_ = i_ * 256 + t;                                                 \
      int d_ = c_ >> 3, s_ = c_ & 7;                                         \
      gld16(Vh + (long)d_ * S_LEN + (k0_) + (s_ ^ (d_ & 7)) * 8,             \
            &lV[buf][c_ * 8]);                                               \
    } } while (0)

__global__ __launch_bounds__(256) void flash_attn_kernel(
    const __hip_bfloat16* __restrict__ Qr, const __hip_bfloat16* __restrict__ Kr,
    const __hip_bfloat16* __restrict__ Vt, __hip_bfloat16* __restrict__ O)
{
  __shared__ __hip_bfloat16 lK[2][64 * 128];   // 2 x 16KB
  __shared__ __hip_bfloat16 lV[2][128 * 64];   // 2 x 16KB
  __shared__ __hip_bfloat16 lP[4][32 * 72];    // per-wave P (32 rows), padded stride
  const int h = blockIdx.y, pair = blockIdx.x;
  const int t = threadIdx.x, w = t >> 6, l = t & 63;
  const int lr = l & 15, lg = l >> 4;
  const __hip_bfloat16* Qh = Qr + (long)h * (S_LEN * HD);
  const __hip_bfloat16* Kh = Kr + (long)h * (S_LEN * HD);
  const __hip_bfloat16* Vh = Vt + (long)h * (HD * S_LEN);
  const float sc2 = 0.12751744f;            // (1/sqrt(128)) * log2(e)

  for (int ph = 0; ph < 2; ++ph) {
    const int qt = ph ? (15 - pair) : pair;
    const int q0 = qt * 128;

    // hoist this q-tile's Q fragments to registers (wave w: rows w*32..+31)
    bf16x8 qf[2][4];
    #pragma unroll
    for (int mi = 0; mi < 2; ++mi)
      #pragma unroll
      for (int ks = 0; ks < 4; ++ks)
        qf[mi][ks] = *(const bf16x8*)(Qh + (long)(q0 + w * 32 + mi * 16 + lr) * HD + ks * 32 + lg * 8);

    float m_r[2][4], l_r[2][4];
    f32x4 oacc[2][8] = {};
    #pragma unroll
    for (int mi = 0; mi < 2; ++mi)
      #pragma unroll
      for (int r = 0; r < 4; ++r) { m_r[mi][r] = -1e30f; l_r[mi][r] = 0.f; }

    const int ktiles = 2 * qt + 2;          // causal: k <= q0+127
    int cur = 0;
    FA_STAGE(0, 0);                         // prologue: tile 0 -> buf0
    __syncthreads();                        // drains vmcnt(0)

    for (int kt = 0; kt < ktiles; ++kt) {
      const int k0 = kt * 64;
      if (kt + 1 < ktiles) FA_STAGE(cur ^ 1, k0 + 64);   // overlap with compute

      // S = Q K^T — kf read once, used by both m-frags
      f32x4 s[2][4] = {};
      #pragma unroll
      for (int ks = 0; ks < 4; ++ks) {
        bf16x8 kf[4];
        #pragma unroll
        for (int nf = 0; nf < 4; ++nf) {
          int row = nf * 16 + lr;
          kf[nf] = *(const bf16x8*)&lK[cur][row * 128 + ((ks * 4 + lg) ^ (row & 15)) * 8];
        }
        #pragma unroll
        for (int mi = 0; mi < 2; ++mi)
          #pragma unroll
          for (int nf = 0; nf < 4; ++nf)
            s[mi][nf] = __builtin_amdgcn_mfma_f32_16x16x32_bf16(qf[mi][ks], kf[nf], s[mi][nf], 0, 0, 0);
      }

      // scale to log2 domain; causal mask only on the two diagonal tiles
      if (kt >= 2 * qt) {
        #pragma unroll
        for (int mi = 0; mi < 2; ++mi)
          #pragma unroll
          for (int nf = 0; nf < 4; ++nf) {
            int k = k0 + nf * 16 + lr;
            #pragma unroll
            for (int r = 0; r < 4; ++r) {
              int q = q0 + w * 32 + mi * 16 + lg * 4 + r;
              float v = s[mi][nf][r] * sc2;
              s[mi][nf][r] = (k > q) ? -1e30f : v;
            }
          }
      } else {
        #pragma unroll
        for (int mi = 0; mi < 2; ++mi)
          #pragma unroll
          for (int nf = 0; nf < 4; ++nf)
            #pragma unroll
            for (int r = 0; r < 4; ++r)
              s[mi][nf][r] *= sc2;
      }

      // defer-max (T13, THR=8 in log2 units): wave-uniform check over both mi
      bool need = false;
      float lm[2][4];
      #pragma unroll
      for (int mi = 0; mi < 2; ++mi)
        #pragma unroll
        for (int r = 0; r < 4; ++r) {
          lm[mi][r] = fmaxf(fmaxf(s[mi][0][r], s[mi][1][r]), fmaxf(s[mi][2][r], s[mi][3][r]));
          need = need || (lm[mi][r] > m_r[mi][r] + 8.f);
        }
      if (__any((int)need)) {
        #pragma unroll
        for (int mi = 0; mi < 2; ++mi)
          #pragma unroll
          for (int r = 0; r < 4; ++r) {
            float mx = lm[mi][r];
            #pragma unroll
            for (int mk = 1; mk < 16; mk <<= 1) mx = fmaxf(mx, __shfl_xor(mx, mk));
            float mo = m_r[mi][r];
            float mn = fmaxf(mo, mx);
            float alpha = exp2f(mo - mn);
            m_r[mi][r] = mn;
            l_r[mi][r] *= alpha;
            #pragma unroll
            for (int df = 0; df < 8; ++df) oacc[mi][df][r] *= alpha;
          }
      }

      // P = exp2(s - m), row-sum (always)
      #pragma unroll
      for (int mi = 0; mi < 2; ++mi)
        #pragma unroll
        for (int r = 0; r < 4; ++r) {
          float rs = 0.f;
          #pragma unroll
          for (int nf = 0; nf < 4; ++nf) {
            float p = exp2f(s[mi][nf][r] - m_r[mi][r]);
            s[mi][nf][r] = p;
            rs += p;
          }
          #pragma unroll
          for (int mk = 1; mk < 16; mk <<= 1) rs += __shfl_xor(rs, mk);
          l_r[mi][r] += rs;
        }

      // P -> LDS (per-wave region), then PV — vf read once, feeds both pa
      #pragma unroll
      for (int mi = 0; mi < 2; ++mi)
        #pragma unroll
        for (int nf = 0; nf < 4; ++nf)
          #pragma unroll
          for (int r = 0; r < 4; ++r)
            lP[w][(mi * 16 + lg * 4 + r) * 72 + nf * 16 + lr] = __float2bfloat16(s[mi][nf][r]);
      asm volatile("s_waitcnt lgkmcnt(0)" ::: "memory");

      #pragma unroll
      for (int ks2 = 0; ks2 < 2; ++ks2) {
        bf16x8 pa0 = *(const bf16x8*)&lP[w][lr * 72 + ks2 * 32 + lg * 8];
        bf16x8 pa1 = *(const bf16x8*)&lP[w][(16 + lr) * 72 + ks2 * 32 + lg * 8];
        #pragma unroll
        for (int df = 0; df < 8; ++df) {
          int row = df * 16 + lr;
          bf16x8 vf = *(const bf16x8*)&lV[cur][row * 64 + ((ks2 * 4 + lg) ^ (row & 7)) * 8];
          oacc[0][df] = __builtin_amdgcn_mfma_f32_16x16x32_bf16(pa0, vf, oacc[0][df], 0, 0, 0);
          oacc[1][df] = __builtin_amdgcn_mfma_f32_16x16x32_bf16(pa1, vf, oacc[1][df], 0, 0, 0);
        }
      }
      __syncthreads();                      // drains next-tile stage (vmcnt 0) + LDS
      cur ^= 1;
    }

    // normalize + write O[s][h*128+d]
    #pragma unroll
    for (int mi = 0; mi < 2; ++mi)
      #pragma unroll
      for (int r = 0; r < 4; ++r) {
        float inv = 1.f / l_r[mi][r];
        long q = q0 + w * 32 + mi * 16 + lg * 4 + r;
        #pragma unroll
        for (int df = 0; df < 8; ++df)
          O[q * HID + h * HD + df * 16 + lr] = __float2bfloat16(oacc[mi][df][r] * inv);
      }
    __syncthreads();                        // phase boundary: lK/lV reuse
  }
}

// ---------- launcher ----------
extern "C" void kernel_launch(void* const* d_in, const int* in_sizes, int n_in,
                              void* d_out, int out_size, void* d_ws, size_t ws_size,
                              hipStream_t stream)
{
  (void)in_sizes; (void)n_in; (void)out_size;
  const float* hidden = (const float*)d_in[0];
  const int*   pos    = (const int*)d_in[1];
  const float* wqkv_w = (const float*)d_in[2];
  const float* wqkv_b = (const float*)d_in[3];
  const float* wo_w   = (const float*)d_in[4];
  const float* wo_b   = (const float*)d_in[5];
  float* out = (float*)d_out;

  // ws layout (bytes). Phase 1: hid_bf | wqkv_bf | qkv_bf.
  // Phase 2+ reuses hid_bf region as Qr, wqkv_bf region as Kr/Vt/Obf/Wo_bf/tables.
  char* ws = (char*)d_ws;
  if (ws_size < 167772160UL) return;        // need 160 MB
  __hip_bfloat16* hid_bf  = (__hip_bfloat16*)(ws + 0);          // 16 MB, later Qr
  __hip_bfloat16* wqkv_bf = (__hip_bfloat16*)(ws + 16777216);   // 96 MB
  __hip_bfloat16* qr      = (__hip_bfloat16*)(ws + 0);
  __hip_bfloat16* kr      = (__hip_bfloat16*)(ws + 16777216);
  __hip_bfloat16* vt      = (__hip_bfloat16*)(ws + 33554432);
  __hip_bfloat16* obf     = (__hip_bfloat16*)(ws + 50331648);
  __hip_bfloat16* wo_bf   = (__hip_bfloat16*)(ws + 67108864);   // 32 MB
  float*          cos_t   = (float*)(ws + 100663296);
  float*          sin_t   = (float*)(ws + 100663296 + 524288);
  __hip_bfloat16* qkv_bf  = (__hip_bfloat16*)(ws + 117440512);  // 48 MB -> total 160 MB

  cvt_bf16_kernel<<<4096, 256, 0, stream>>>(hidden, hid_bf, 8388608L);
  cvt_bf16_kernel<<<8192, 256, 0, stream>>>(wqkv_w, wqkv_bf, 50331648L);
  gemm_bt_kernel<1><<<dim3(16, 96), 256, 0, stream>>>(hid_bf, wqkv_bf, wqkv_b, qkv_bf, 2048, 12288, 4096);
  // safe to overwrite wqkv region only after the QKV GEMM
  cvt_bf16_kernel<<<8192, 256, 0, stream>>>(wo_w, wo_bf, 16777216L);
  rope_table_kernel<<<2048, 64, 0, stream>>>(pos, cos_t, sin_t);
  rope_rearrange_kernel<<<dim3(32, 32), 256, 0, stream>>>(qkv_bf, cos_t, sin_t, qr, kr, vt);
  flash_attn_kernel<<<dim3(8, 32), 256, 0, stream>>>(qr, kr, vt, obf);
  gemm_bt_kernel<0><<<dim3(16, 32), 256, 0, stream>>>(obf, wo_bf, wo_b, out, 2048, 4096, 4096);
}

// Round 15
// 475.173 us; speedup vs baseline: 1.0457x; 1.0457x over previous
//
#include <hip/hip_runtime.h>
#include <hip/hip_bf16.h>

// ---------- types ----------
typedef short bf16x8 __attribute__((ext_vector_type(8)));   // 8 bf16 (4 VGPRs)
typedef float f32x4  __attribute__((ext_vector_type(4)));

typedef __attribute__((address_space(1))) const unsigned int gu32_t;
typedef __attribute__((address_space(3))) unsigned int lu32_t;

__device__ inline void gld16(const void* g, void* l) {
  // async global->LDS, 16B per lane; dest must be wave-uniform-base + lane*16
  __builtin_amdgcn_global_load_lds((gu32_t*)g, (lu32_t*)l, 16, 0, 0);
}

__device__ inline float bf2f(__hip_bfloat16 x) { return __bfloat162float(x); }

#define S_LEN 2048
#define HID   4096
#define NH    32
#define HD    128
#define QKV_N 12288

// ---------- fp32 -> bf16 convert (vectorized, grid-stride) ----------
__global__ void cvt_bf16_kernel(const float* __restrict__ in,
                                __hip_bfloat16* __restrict__ out, long n) {
  long stride = (long)gridDim.x * blockDim.x;
  for (long i = (long)blockIdx.x * blockDim.x + threadIdx.x; i * 8 < n; i += stride) {
    long b = i * 8;
    float4 a0 = *(const float4*)(in + b);
    float4 a1 = *(const float4*)(in + b + 4);
    union { __hip_bfloat16 h[8]; bf16x8 v; } u;
    u.h[0] = __float2bfloat16(a0.x); u.h[1] = __float2bfloat16(a0.y);
    u.h[2] = __float2bfloat16(a0.z); u.h[3] = __float2bfloat16(a0.w);
    u.h[4] = __float2bfloat16(a1.x); u.h[5] = __float2bfloat16(a1.y);
    u.h[6] = __float2bfloat16(a1.z); u.h[7] = __float2bfloat16(a1.w);
    *(bf16x8*)(out + b) = u.v;
  }
}

// ---------- GEMM (m97 structure, 900 TF = structural ceiling here) ----------
// T1 XCD chunk swizzle (FETCH 420->200MB, R13) + T2 LDS swizzle (R5).
// Compute-bound at MfmaUtil 42 + VALUBusy 49; frozen.
template<int WRITE_BF16>
__global__ __launch_bounds__(256) void gemm_bt_kernel(
    const __hip_bfloat16* __restrict__ A,
    const __hip_bfloat16* __restrict__ B,
    const float* __restrict__ bias,
    void* __restrict__ Cout, int M, int N, int K)
{
  __shared__ __hip_bfloat16 lA[128 * 64];
  __shared__ __hip_bfloat16 lB[128 * 64];
  const int t = threadIdx.x;
  const int w = t >> 6, l = t & 63;
  const int lr = l & 15, lg = l >> 4;
  const int nwg = gridDim.x * gridDim.y;
  const int bid = blockIdx.y * gridDim.x + blockIdx.x;
  const int swz = (bid & 7) * (nwg >> 3) + (bid >> 3);   // XCD chunk swizzle
  const int m0 = (swz % gridDim.x) * 128, n0 = (swz / gridDim.x) * 128;
  const int wm = (w >> 1) * 64, wn = (w & 1) * 64;

  f32x4 acc[4][4] = {};

  for (int k0 = 0; k0 < K; k0 += 64) {
    #pragma unroll
    for (int i = 0; i < 4; ++i) {
      int c = i * 256 + t;            // chunk id 0..1023, 16B each, linear in LDS
      int row = c >> 3, s = c & 7;    // source slot pre-swizzled: s ^ (row&7)
      gld16(A + (long)(m0 + row) * K + k0 + (s ^ (row & 7)) * 8, &lA[c * 8]);
    }
    #pragma unroll
    for (int i = 0; i < 4; ++i) {
      int c = i * 256 + t;
      int row = c >> 3, s = c & 7;
      gld16(B + (long)(n0 + row) * K + k0 + (s ^ (row & 7)) * 8, &lB[c * 8]);
    }
    __syncthreads();                  // drains vmcnt before barrier
    #pragma unroll
    for (int ks = 0; ks < 2; ++ks) {
      bf16x8 af[4], bfr[4];
      #pragma unroll
      for (int mi = 0; mi < 4; ++mi) {
        int row = wm + mi * 16 + lr;
        af[mi] = *(const bf16x8*)&lA[row * 64 + ((ks * 4 + lg) ^ (row & 7)) * 8];
      }
      #pragma unroll
      for (int ni = 0; ni < 4; ++ni) {
        int row = wn + ni * 16 + lr;
        bfr[ni] = *(const bf16x8*)&lB[row * 64 + ((ks * 4 + lg) ^ (row & 7)) * 8];
      }
      #pragma unroll
      for (int mi = 0; mi < 4; ++mi)
        #pragma unroll
        for (int ni = 0; ni < 4; ++ni)
          acc[mi][ni] = __builtin_amdgcn_mfma_f32_16x16x32_bf16(af[mi], bfr[ni], acc[mi][ni], 0, 0, 0);
    }
    __syncthreads();
  }

  #pragma unroll
  for (int mi = 0; mi < 4; ++mi) {
    #pragma unroll
    for (int ni = 0; ni < 4; ++ni) {
      int col = n0 + wn + ni * 16 + lr;
      float bv = bias[col];
      #pragma unroll
      for (int r = 0; r < 4; ++r) {
        int row = m0 + wm + mi * 16 + lg * 4 + r;     // C/D: col=lane&15, row=(lane>>4)*4+reg
        float v = acc[mi][ni][r] + bv;
        if (WRITE_BF16)
          ((__hip_bfloat16*)Cout)[(long)row * N + col] = __float2bfloat16(v);
        else
          ((float*)Cout)[(long)row * N + col] = v;
      }
    }
  }
}

// ---------- RoPE cos/sin table: [s][64] ----------
__global__ void rope_table_kernel(const int* __restrict__ pos,
                                  float* __restrict__ ct, float* __restrict__ st) {
  int s = blockIdx.x, j = threadIdx.x;      // 2048 x 64
  float p = (float)pos[s];
  float invf = exp2f(-0.20762050593046013f * (float)j);
  float a = p * invf;
  ct[s * 64 + j] = cosf(a);
  st[s * 64 + j] = sinf(a);
}

// ---------- RoPE + rearrange (vectorized, R13) ----------
__global__ __launch_bounds__(256) void rope_rearrange_kernel(
    const __hip_bfloat16* __restrict__ qkv,
    const float* __restrict__ ct, const float* __restrict__ st,
    __hip_bfloat16* __restrict__ Qr, __hip_bfloat16* __restrict__ Kr,
    __hip_bfloat16* __restrict__ Vt)
{
  __shared__ __hip_bfloat16 lv[64][136];    // padded to break bank conflicts on transpose read
  const int h = blockIdx.y, s0 = blockIdx.x * 64, t = threadIdx.x;

  #pragma unroll
  for (int half = 0; half < 2; ++half) {
    int si = half * 32 + (t >> 3);          // row within tile
    int jo = (t & 7) * 8;                   // 8 consecutive j per lane
    long base = (long)(s0 + si) * QKV_N + h * 384;
    union { __hip_bfloat16 h8[8]; bf16x8 v; } q1, q2, k1, k2, o;
    q1.v = *(const bf16x8*)(qkv + base + jo);
    q2.v = *(const bf16x8*)(qkv + base + 64 + jo);
    k1.v = *(const bf16x8*)(qkv + base + 128 + jo);
    k2.v = *(const bf16x8*)(qkv + base + 192 + jo);
    const float* cp = ct + (s0 + si) * 64 + jo;
    const float* sp = st + (s0 + si) * 64 + jo;
    long ob = (long)h * (S_LEN * HD) + (long)(s0 + si) * HD;
    #pragma unroll
    for (int e = 0; e < 8; ++e)
      o.h8[e] = __float2bfloat16(bf2f(q1.h8[e]) * cp[e] - bf2f(q2.h8[e]) * sp[e]);
    *(bf16x8*)(Qr + ob + jo) = o.v;
    #pragma unroll
    for (int e = 0; e < 8; ++e)
      o.h8[e] = __float2bfloat16(bf2f(q2.h8[e]) * cp[e] + bf2f(q1.h8[e]) * sp[e]);
    *(bf16x8*)(Qr + ob + 64 + jo) = o.v;
    #pragma unroll
    for (int e = 0; e < 8; ++e)
      o.h8[e] = __float2bfloat16(bf2f(k1.h8[e]) * cp[e] - bf2f(k2.h8[e]) * sp[e]);
    *(bf16x8*)(Kr + ob + jo) = o.v;
    #pragma unroll
    for (int e = 0; e < 8; ++e)
      o.h8[e] = __float2bfloat16(bf2f(k2.h8[e]) * cp[e] + bf2f(k1.h8[e]) * sp[e]);
    *(bf16x8*)(Kr + ob + 64 + jo) = o.v;
    *(bf16x8*)&lv[si][jo]      = *(const bf16x8*)(qkv + base + 256 + jo);
    *(bf16x8*)&lv[si][64 + jo] = *(const bf16x8*)(qkv + base + 320 + jo);
  }
  __syncthreads();
  #pragma unroll
  for (int i = 0; i < 4; ++i) {
    int c = i * 256 + t;                    // 128 d x 8 chunks of 8 s
    int d = c >> 3, s8 = (c & 7) * 8;
    union { __hip_bfloat16 h8[8]; bf16x8 v; } u;
    #pragma unroll
    for (int j2 = 0; j2 < 8; ++j2) u.h8[j2] = lv[s8 + j2][d];
    *(bf16x8*)(Vt + (long)h * (HD * S_LEN) + (long)d * S_LEN + s0 + s8) = u.v;
  }
}

// ---------- causal flash attention (R13 config, reverted from R14) ----------
// QBLK=64, paired q-tiles {p, 31-p} -> 33 k-tiles/block uniform, grid 16x32
// = 512 blocks (2/CU, 2 waves/SIMD — R14's QBLK=128 dropped to 1 wave/SIMD
// and regressed; reverted). K/V double-buffered; R12 softmax (log2 domain,
// diagonal-only mask, T13 defer-max THR=8).
// ROUND 15: + T5 s_setprio(1) around QK and PV MFMA clusters (m191: +4-7%
// on attn with independent multi-wave blocks; our waves sync only once per
// k-tile, so the scheduler has load-phase/MFMA-phase diversity to arbitrate).
// lK: 16 slots/row swizzle row&15; lV: 8 slots/row swizzle row&7 (T2).
#define FA_STAGE(buf, k0_) do {                                              \
    _Pragma("unroll")                                                        \
    for (int i_ = 0; i_ < 4; ++i_) {       /* K tile: 64 k x 128 d */        \
      int c_ = i_ * 256 + t;                                                 \
      int row_ = c_ >> 4, s_ = c_ & 15;                                      \
      gld16(Kh + (long)((k0_) + row_) * HD + (s_ ^ (row_ & 15)) * 8,         \
            &lK[buf][c_ * 8]);                                               \
    }                                                                        \
    _Pragma("unroll")                                                        \
    for (int i_ = 0; i_ < 4; ++i_) {       /* V^T tile: 128 d x 64 k */      \
      int c_ = i_ * 256 + t;                                                 \
      int d_ = c_ >> 3, s_ = c_ & 7;                                         \
      gld16(Vh + (long)d_ * S_LEN + (k0_) + (s_ ^ (d_ & 7)) * 8,             \
            &lV[buf][c_ * 8]);                                               \
    } } while (0)

__global__ __launch_bounds__(256) void flash_attn_kernel(
    const __hip_bfloat16* __restrict__ Qr, const __hip_bfloat16* __restrict__ Kr,
    const __hip_bfloat16* __restrict__ Vt, __hip_bfloat16* __restrict__ O)
{
  __shared__ __hip_bfloat16 lK[2][64 * 128];   // 2 x 16KB
  __shared__ __hip_bfloat16 lV[2][128 * 64];   // 2 x 16KB
  __shared__ __hip_bfloat16 lP[4][16 * 72];    // per-wave P, padded stride
  const int h = blockIdx.y, pair = blockIdx.x;
  const int t = threadIdx.x, w = t >> 6, l = t & 63;
  const int lr = l & 15, lg = l >> 4;
  const __hip_bfloat16* Qh = Qr + (long)h * (S_LEN * HD);
  const __hip_bfloat16* Kh = Kr + (long)h * (S_LEN * HD);
  const __hip_bfloat16* Vh = Vt + (long)h * (HD * S_LEN);
  const float sc2 = 0.12751744f;            // (1/sqrt(128)) * log2(e)

  for (int ph = 0; ph < 2; ++ph) {
    const int qt = ph ? (31 - pair) : pair;
    const int q0 = qt * 64;

    // hoist this q-tile's Q fragments to registers
    bf16x8 qf[4];
    #pragma unroll
    for (int ks = 0; ks < 4; ++ks)
      qf[ks] = *(const bf16x8*)(Qh + (long)(q0 + w * 16 + lr) * HD + ks * 32 + lg * 8);

    float m_r[4], l_r[4];
    f32x4 oacc[8] = {};
    #pragma unroll
    for (int r = 0; r < 4; ++r) { m_r[r] = -1e30f; l_r[r] = 0.f; }

    const int ktiles = qt + 1;              // causal: k <= q0+63
    int cur = 0;
    FA_STAGE(0, 0);                         // prologue: tile 0 -> buf0
    __syncthreads();                        // drains vmcnt(0)

    for (int kt = 0; kt < ktiles; ++kt) {
      const int k0 = kt * 64;
      if (kt + 1 < ktiles) FA_STAGE(cur ^ 1, k0 + 64);   // overlap with compute

      // S = Q K^T (one 16-row m-frag per wave), setprio around MFMA cluster
      f32x4 s[4] = {};
      #pragma unroll
      for (int ks = 0; ks < 4; ++ks) {
        bf16x8 kf[4];
        #pragma unroll
        for (int nf = 0; nf < 4; ++nf) {
          int row = nf * 16 + lr;
          kf[nf] = *(const bf16x8*)&lK[cur][row * 128 + ((ks * 4 + lg) ^ (row & 15)) * 8];
        }
        __builtin_amdgcn_s_setprio(1);
        #pragma unroll
        for (int nf = 0; nf < 4; ++nf)
          s[nf] = __builtin_amdgcn_mfma_f32_16x16x32_bf16(qf[ks], kf[nf], s[nf], 0, 0, 0);
        __builtin_amdgcn_s_setprio(0);
      }

      // scale to log2 domain; causal mask only on the diagonal tile
      if (kt == qt) {
        #pragma unroll
        for (int nf = 0; nf < 4; ++nf) {
          int k = k0 + nf * 16 + lr;
          #pragma unroll
          for (int r = 0; r < 4; ++r) {
            int q = q0 + w * 16 + lg * 4 + r;
            float v = s[nf][r] * sc2;
            s[nf][r] = (k > q) ? -1e30f : v;
          }
        }
      } else {
        #pragma unroll
        for (int nf = 0; nf < 4; ++nf)
          #pragma unroll
          for (int r = 0; r < 4; ++r)
            s[nf][r] *= sc2;
      }

      // defer-max (T13, THR=8 in log2 units): wave-uniform check
      bool need = false;
      float lm[4];
      #pragma unroll
      for (int r = 0; r < 4; ++r) {
        lm[r] = fmaxf(fmaxf(s[0][r], s[1][r]), fmaxf(s[2][r], s[3][r]));
        need = need || (lm[r] > m_r[r] + 8.f);
      }
      if (__any((int)need)) {
        #pragma unroll
        for (int r = 0; r < 4; ++r) {
          float mx = lm[r];
          #pragma unroll
          for (int mk = 1; mk < 16; mk <<= 1) mx = fmaxf(mx, __shfl_xor(mx, mk));
          float mo = m_r[r];
          float mn = fmaxf(mo, mx);
          float alpha = exp2f(mo - mn);
          m_r[r] = mn;
          l_r[r] *= alpha;
          #pragma unroll
          for (int df = 0; df < 8; ++df) oacc[df][r] *= alpha;
        }
      }

      // P = exp2(s - m), row-sum (always)
      #pragma unroll
      for (int r = 0; r < 4; ++r) {
        float rs = 0.f;
        #pragma unroll
        for (int nf = 0; nf < 4; ++nf) {
          float p = exp2f(s[nf][r] - m_r[r]);
          s[nf][r] = p;
          rs += p;
        }
        #pragma unroll
        for (int mk = 1; mk < 16; mk <<= 1) rs += __shfl_xor(rs, mk);
        l_r[r] += rs;
      }

      // P -> LDS (per-wave region), then PV (setprio around MFMA cluster)
      #pragma unroll
      for (int nf = 0; nf < 4; ++nf)
        #pragma unroll
        for (int r = 0; r < 4; ++r)
          lP[w][(lg * 4 + r) * 72 + nf * 16 + lr] = __float2bfloat16(s[nf][r]);
      asm volatile("s_waitcnt lgkmcnt(0)" ::: "memory");

      #pragma unroll
      for (int ks2 = 0; ks2 < 2; ++ks2) {
        bf16x8 pa = *(const bf16x8*)&lP[w][lr * 72 + ks2 * 32 + lg * 8];
        __builtin_amdgcn_s_setprio(1);
        #pragma unroll
        for (int df = 0; df < 8; ++df) {
          int row = df * 16 + lr;
          bf16x8 vf = *(const bf16x8*)&lV[cur][row * 64 + ((ks2 * 4 + lg) ^ (row & 7)) * 8];
          oacc[df] = __builtin_amdgcn_mfma_f32_16x16x32_bf16(pa, vf, oacc[df], 0, 0, 0);
        }
        __builtin_amdgcn_s_setprio(0);
      }
      __syncthreads();                      // drains next-tile stage (vmcnt 0) + LDS
      cur ^= 1;
    }

    // normalize + write O[s][h*128+d]
    #pragma unroll
    for (int r = 0; r < 4; ++r) {
      float inv = 1.f / l_r[r];
      long q = q0 + w * 16 + lg * 4 + r;
      #pragma unroll
      for (int df = 0; df < 8; ++df)
        O[q * HID + h * HD + df * 16 + lr] = __float2bfloat16(oacc[df][r] * inv);
    }
    __syncthreads();                        // phase boundary: lK/lV reuse
  }
}

// ---------- launcher ----------
extern "C" void kernel_launch(void* const* d_in, const int* in_sizes, int n_in,
                              void* d_out, int out_size, void* d_ws, size_t ws_size,
                              hipStream_t stream)
{
  (void)in_sizes; (void)n_in; (void)out_size;
  const float* hidden = (const float*)d_in[0];
  const int*   pos    = (const int*)d_in[1];
  const float* wqkv_w = (const float*)d_in[2];
  const float* wqkv_b = (const float*)d_in[3];
  const float* wo_w   = (const float*)d_in[4];
  const float* wo_b   = (const float*)d_in[5];
  float* out = (float*)d_out;

  // ws layout (bytes). Phase 1: hid_bf | wqkv_bf | qkv_bf.
  // Phase 2+ reuses hid_bf region as Qr, wqkv_bf region as Kr/Vt/Obf/Wo_bf/tables.
  char* ws = (char*)d_ws;
  if (ws_size < 167772160UL) return;        // need 160 MB
  __hip_bfloat16* hid_bf  = (__hip_bfloat16*)(ws + 0);          // 16 MB, later Qr
  __hip_bfloat16* wqkv_bf = (__hip_bfloat16*)(ws + 16777216);   // 96 MB
  __hip_bfloat16* qr      = (__hip_bfloat16*)(ws + 0);
  __hip_bfloat16* kr      = (__hip_bfloat16*)(ws + 16777216);
  __hip_bfloat16* vt      = (__hip_bfloat16*)(ws + 33554432);
  __hip_bfloat16* obf     = (__hip_bfloat16*)(ws + 50331648);
  __hip_bfloat16* wo_bf   = (__hip_bfloat16*)(ws + 67108864);   // 32 MB
  float*          cos_t   = (float*)(ws + 100663296);
  float*          sin_t   = (float*)(ws + 100663296 + 524288);
  __hip_bfloat16* qkv_bf  = (__hip_bfloat16*)(ws + 117440512);  // 48 MB -> total 160 MB

  cvt_bf16_kernel<<<4096, 256, 0, stream>>>(hidden, hid_bf, 8388608L);
  cvt_bf16_kernel<<<8192, 256, 0, stream>>>(wqkv_w, wqkv_bf, 50331648L);
  gemm_bt_kernel<1><<<dim3(16, 96), 256, 0, stream>>>(hid_bf, wqkv_bf, wqkv_b, qkv_bf, 2048, 12288, 4096);
  // safe to overwrite wqkv region only after the QKV GEMM
  cvt_bf16_kernel<<<8192, 256, 0, stream>>>(wo_w, wo_bf, 16777216L);
  rope_table_kernel<<<2048, 64, 0, stream>>>(pos, cos_t, sin_t);
  rope_rearrange_kernel<<<dim3(32, 32), 256, 0, stream>>>(qkv_bf, cos_t, sin_t, qr, kr, vt);
  flash_attn_kernel<<<dim3(16, 32), 256, 0, stream>>>(qr, kr, vt, obf);
  gemm_bt_kernel<0><<<dim3(16, 32), 256, 0, stream>>>(obf, wo_bf, wo_b, out, 2048, 4096, 4096);
}

// Round 16
// 462.731 us; speedup vs baseline: 1.0738x; 1.0269x over previous
//
#include <hip/hip_runtime.h>
#include <hip/hip_bf16.h>

// ---------- types ----------
typedef short bf16x8 __attribute__((ext_vector_type(8)));   // 8 bf16 (4 VGPRs)
typedef float f32x4  __attribute__((ext_vector_type(4)));
typedef float f32x16 __attribute__((ext_vector_type(16)));  // 32x32 MFMA acc

typedef __attribute__((address_space(1))) const unsigned int gu32_t;
typedef __attribute__((address_space(3))) unsigned int lu32_t;

__device__ inline void gld16(const void* g, void* l) {
  // async global->LDS, 16B per lane; dest must be wave-uniform-base + lane*16
  __builtin_amdgcn_global_load_lds((gu32_t*)g, (lu32_t*)l, 16, 0, 0);
}

__device__ inline float bf2f(__hip_bfloat16 x) { return __bfloat162float(x); }

#define S_LEN 2048
#define HID   4096
#define NH    32
#define HD    128
#define QKV_N 12288

// ---------- fp32 -> bf16 convert (vectorized, grid-stride) ----------
__global__ void cvt_bf16_kernel(const float* __restrict__ in,
                                __hip_bfloat16* __restrict__ out, long n) {
  long stride = (long)gridDim.x * blockDim.x;
  for (long i = (long)blockIdx.x * blockDim.x + threadIdx.x; i * 8 < n; i += stride) {
    long b = i * 8;
    float4 a0 = *(const float4*)(in + b);
    float4 a1 = *(const float4*)(in + b + 4);
    union { __hip_bfloat16 h[8]; bf16x8 v; } u;
    u.h[0] = __float2bfloat16(a0.x); u.h[1] = __float2bfloat16(a0.y);
    u.h[2] = __float2bfloat16(a0.z); u.h[3] = __float2bfloat16(a0.w);
    u.h[4] = __float2bfloat16(a1.x); u.h[5] = __float2bfloat16(a1.y);
    u.h[6] = __float2bfloat16(a1.z); u.h[7] = __float2bfloat16(a1.w);
    *(bf16x8*)(out + b) = u.v;
  }
}

// ---------- GEMM (m97 structure + 32x32x16 MFMA): C = A B^T + bias ----------
// ROUND 16: switch 16x16x32 -> 32x32x16 MFMA. Same LDS bytes/reads per
// K-step (16 x ds_read_b128), but 16 MFMA x 8.07cyc = 129 cyc vs 32 x 4.85
// = 155 -> +20% FLOP/cyc on the MFMA pipe, half the issue slots.
// A/B frag (by analogy with verified 16x16 pattern): row = lane&31,
// k = (lane>>5)*8 + e (contiguous 8). C/D (m74/m101 verified):
// col = lane&31, row = (reg&3) + 8*(reg>>2) + 4*(lane>>5).
// Conflict audit: within any 8 consecutive lanes rows are consecutive ->
// row&7 distinct -> slot=(kk*2+(l>>5))^(row&7) distinct -> conflict-free
// (same 8-lane-phase property as the measured-0-conflict 16x16 pattern).
// T1 XCD chunk swizzle (R13) + T2 source/read swizzle (R5) unchanged.
template<int WRITE_BF16>
__global__ __launch_bounds__(256) void gemm_bt_kernel(
    const __hip_bfloat16* __restrict__ A,
    const __hip_bfloat16* __restrict__ B,
    const float* __restrict__ bias,
    void* __restrict__ Cout, int M, int N, int K)
{
  __shared__ __hip_bfloat16 lA[128 * 64];
  __shared__ __hip_bfloat16 lB[128 * 64];
  const int t = threadIdx.x;
  const int w = t >> 6, l = t & 63;
  const int l31 = l & 31, lh = l >> 5;
  const int nwg = gridDim.x * gridDim.y;
  const int bid = blockIdx.y * gridDim.x + blockIdx.x;
  const int swz = (bid & 7) * (nwg >> 3) + (bid >> 3);   // XCD chunk swizzle
  const int m0 = (swz % gridDim.x) * 128, n0 = (swz / gridDim.x) * 128;
  const int wm = (w >> 1) * 64, wn = (w & 1) * 64;

  f32x16 acc[2][2] = {};

  for (int k0 = 0; k0 < K; k0 += 64) {
    #pragma unroll
    for (int i = 0; i < 4; ++i) {
      int c = i * 256 + t;            // chunk id 0..1023, 16B each, linear in LDS
      int row = c >> 3, s = c & 7;    // source slot pre-swizzled: s ^ (row&7)
      gld16(A + (long)(m0 + row) * K + k0 + (s ^ (row & 7)) * 8, &lA[c * 8]);
    }
    #pragma unroll
    for (int i = 0; i < 4; ++i) {
      int c = i * 256 + t;
      int row = c >> 3, s = c & 7;
      gld16(B + (long)(n0 + row) * K + k0 + (s ^ (row & 7)) * 8, &lB[c * 8]);
    }
    __syncthreads();                  // drains vmcnt before barrier
    #pragma unroll
    for (int kk = 0; kk < 4; ++kk) {  // K=16 per MFMA, 4 per K-step
      bf16x8 af[2], bfr[2];
      #pragma unroll
      for (int mt = 0; mt < 2; ++mt) {
        int row = wm + mt * 32 + l31;
        int slot = (kk * 2 + lh) ^ (row & 7);
        af[mt] = *(const bf16x8*)&lA[row * 64 + slot * 8];
      }
      #pragma unroll
      for (int nt = 0; nt < 2; ++nt) {
        int row = wn + nt * 32 + l31;
        int slot = (kk * 2 + lh) ^ (row & 7);
        bfr[nt] = *(const bf16x8*)&lB[row * 64 + slot * 8];
      }
      #pragma unroll
      for (int mt = 0; mt < 2; ++mt)
        #pragma unroll
        for (int nt = 0; nt < 2; ++nt)
          acc[mt][nt] = __builtin_amdgcn_mfma_f32_32x32x16_bf16(af[mt], bfr[nt], acc[mt][nt], 0, 0, 0);
    }
    __syncthreads();
  }

  #pragma unroll
  for (int mt = 0; mt < 2; ++mt) {
    #pragma unroll
    for (int nt = 0; nt < 2; ++nt) {
      int col = n0 + wn + nt * 32 + l31;
      float bv = bias[col];
      #pragma unroll
      for (int reg = 0; reg < 16; ++reg) {
        // C/D 32x32: col=lane&31, row=(reg&3)+8*(reg>>2)+4*(lane>>5)
        int row = m0 + wm + mt * 32 + (reg & 3) + 8 * (reg >> 2) + 4 * lh;
        float v = acc[mt][nt][reg] + bv;
        if (WRITE_BF16)
          ((__hip_bfloat16*)Cout)[(long)row * N + col] = __float2bfloat16(v);
        else
          ((float*)Cout)[(long)row * N + col] = v;
      }
    }
  }
}

// ---------- RoPE cos/sin table: [s][64] ----------
__global__ void rope_table_kernel(const int* __restrict__ pos,
                                  float* __restrict__ ct, float* __restrict__ st) {
  int s = blockIdx.x, j = threadIdx.x;      // 2048 x 64
  float p = (float)pos[s];
  float invf = exp2f(-0.20762050593046013f * (float)j);
  float a = p * invf;
  ct[s * 64 + j] = cosf(a);
  st[s * 64 + j] = sinf(a);
}

// ---------- RoPE + rearrange (vectorized, R13) ----------
__global__ __launch_bounds__(256) void rope_rearrange_kernel(
    const __hip_bfloat16* __restrict__ qkv,
    const float* __restrict__ ct, const float* __restrict__ st,
    __hip_bfloat16* __restrict__ Qr, __hip_bfloat16* __restrict__ Kr,
    __hip_bfloat16* __restrict__ Vt)
{
  __shared__ __hip_bfloat16 lv[64][136];    // padded to break bank conflicts on transpose read
  const int h = blockIdx.y, s0 = blockIdx.x * 64, t = threadIdx.x;

  #pragma unroll
  for (int half = 0; half < 2; ++half) {
    int si = half * 32 + (t >> 3);          // row within tile
    int jo = (t & 7) * 8;                   // 8 consecutive j per lane
    long base = (long)(s0 + si) * QKV_N + h * 384;
    union { __hip_bfloat16 h8[8]; bf16x8 v; } q1, q2, k1, k2, o;
    q1.v = *(const bf16x8*)(qkv + base + jo);
    q2.v = *(const bf16x8*)(qkv + base + 64 + jo);
    k1.v = *(const bf16x8*)(qkv + base + 128 + jo);
    k2.v = *(const bf16x8*)(qkv + base + 192 + jo);
    const float* cp = ct + (s0 + si) * 64 + jo;
    const float* sp = st + (s0 + si) * 64 + jo;
    long ob = (long)h * (S_LEN * HD) + (long)(s0 + si) * HD;
    #pragma unroll
    for (int e = 0; e < 8; ++e)
      o.h8[e] = __float2bfloat16(bf2f(q1.h8[e]) * cp[e] - bf2f(q2.h8[e]) * sp[e]);
    *(bf16x8*)(Qr + ob + jo) = o.v;
    #pragma unroll
    for (int e = 0; e < 8; ++e)
      o.h8[e] = __float2bfloat16(bf2f(q2.h8[e]) * cp[e] + bf2f(q1.h8[e]) * sp[e]);
    *(bf16x8*)(Qr + ob + 64 + jo) = o.v;
    #pragma unroll
    for (int e = 0; e < 8; ++e)
      o.h8[e] = __float2bfloat16(bf2f(k1.h8[e]) * cp[e] - bf2f(k2.h8[e]) * sp[e]);
    *(bf16x8*)(Kr + ob + jo) = o.v;
    #pragma unroll
    for (int e = 0; e < 8; ++e)
      o.h8[e] = __float2bfloat16(bf2f(k2.h8[e]) * cp[e] + bf2f(k1.h8[e]) * sp[e]);
    *(bf16x8*)(Kr + ob + 64 + jo) = o.v;
    *(bf16x8*)&lv[si][jo]      = *(const bf16x8*)(qkv + base + 256 + jo);
    *(bf16x8*)&lv[si][64 + jo] = *(const bf16x8*)(qkv + base + 320 + jo);
  }
  __syncthreads();
  #pragma unroll
  for (int i = 0; i < 4; ++i) {
    int c = i * 256 + t;                    // 128 d x 8 chunks of 8 s
    int d = c >> 3, s8 = (c & 7) * 8;
    union { __hip_bfloat16 h8[8]; bf16x8 v; } u;
    #pragma unroll
    for (int j2 = 0; j2 < 8; ++j2) u.h8[j2] = lv[s8 + j2][d];
    *(bf16x8*)(Vt + (long)h * (HD * S_LEN) + (long)d * S_LEN + s0 + s8) = u.v;
  }
}

// ---------- causal flash attention (R15 config: frozen) ----------
// QBLK=64, paired q-tiles {p, 31-p} -> 33 k-tiles/block uniform, grid 16x32.
// K/V dbuf; log2 softmax, diagonal-only mask, T13 defer-max; T5 setprio.
// lK: 16 slots/row swizzle row&15; lV: 8 slots/row swizzle row&7 (T2).
#define FA_STAGE(buf, k0_) do {                                              \
    _Pragma("unroll")                                                        \
    for (int i_ = 0; i_ < 4; ++i_) {       /* K tile: 64 k x 128 d */        \
      int c_ = i_ * 256 + t;                                                 \
      int row_ = c_ >> 4, s_ = c_ & 15;                                      \
      gld16(Kh + (long)((k0_) + row_) * HD + (s_ ^ (row_ & 15)) * 8,         \
            &lK[buf][c_ * 8]);                                               \
    }                                                                        \
    _Pragma("unroll")                                                        \
    for (int i_ = 0; i_ < 4; ++i_) {       /* V^T tile: 128 d x 64 k */      \
      int c_ = i_ * 256 + t;                                                 \
      int d_ = c_ >> 3, s_ = c_ & 7;                                         \
      gld16(Vh + (long)d_ * S_LEN + (k0_) + (s_ ^ (d_ & 7)) * 8,             \
            &lV[buf][c_ * 8]);                                               \
    } } while (0)

__global__ __launch_bounds__(256) void flash_attn_kernel(
    const __hip_bfloat16* __restrict__ Qr, const __hip_bfloat16* __restrict__ Kr,
    const __hip_bfloat16* __restrict__ Vt, __hip_bfloat16* __restrict__ O)
{
  __shared__ __hip_bfloat16 lK[2][64 * 128];   // 2 x 16KB
  __shared__ __hip_bfloat16 lV[2][128 * 64];   // 2 x 16KB
  __shared__ __hip_bfloat16 lP[4][16 * 72];    // per-wave P, padded stride
  const int h = blockIdx.y, pair = blockIdx.x;
  const int t = threadIdx.x, w = t >> 6, l = t & 63;
  const int lr = l & 15, lg = l >> 4;
  const __hip_bfloat16* Qh = Qr + (long)h * (S_LEN * HD);
  const __hip_bfloat16* Kh = Kr + (long)h * (S_LEN * HD);
  const __hip_bfloat16* Vh = Vt + (long)h * (HD * S_LEN);
  const float sc2 = 0.12751744f;            // (1/sqrt(128)) * log2(e)

  for (int ph = 0; ph < 2; ++ph) {
    const int qt = ph ? (31 - pair) : pair;
    const int q0 = qt * 64;

    // hoist this q-tile's Q fragments to registers
    bf16x8 qf[4];
    #pragma unroll
    for (int ks = 0; ks < 4; ++ks)
      qf[ks] = *(const bf16x8*)(Qh + (long)(q0 + w * 16 + lr) * HD + ks * 32 + lg * 8);

    float m_r[4], l_r[4];
    f32x4 oacc[8] = {};
    #pragma unroll
    for (int r = 0; r < 4; ++r) { m_r[r] = -1e30f; l_r[r] = 0.f; }

    const int ktiles = qt + 1;              // causal: k <= q0+63
    int cur = 0;
    FA_STAGE(0, 0);                         // prologue: tile 0 -> buf0
    __syncthreads();                        // drains vmcnt(0)

    for (int kt = 0; kt < ktiles; ++kt) {
      const int k0 = kt * 64;
      if (kt + 1 < ktiles) FA_STAGE(cur ^ 1, k0 + 64);   // overlap with compute

      // S = Q K^T (one 16-row m-frag per wave), setprio around MFMA cluster
      f32x4 s[4] = {};
      #pragma unroll
      for (int ks = 0; ks < 4; ++ks) {
        bf16x8 kf[4];
        #pragma unroll
        for (int nf = 0; nf < 4; ++nf) {
          int row = nf * 16 + lr;
          kf[nf] = *(const bf16x8*)&lK[cur][row * 128 + ((ks * 4 + lg) ^ (row & 15)) * 8];
        }
        __builtin_amdgcn_s_setprio(1);
        #pragma unroll
        for (int nf = 0; nf < 4; ++nf)
          s[nf] = __builtin_amdgcn_mfma_f32_16x16x32_bf16(qf[ks], kf[nf], s[nf], 0, 0, 0);
        __builtin_amdgcn_s_setprio(0);
      }

      // scale to log2 domain; causal mask only on the diagonal tile
      if (kt == qt) {
        #pragma unroll
        for (int nf = 0; nf < 4; ++nf) {
          int k = k0 + nf * 16 + lr;
          #pragma unroll
          for (int r = 0; r < 4; ++r) {
            int q = q0 + w * 16 + lg * 4 + r;
            float v = s[nf][r] * sc2;
            s[nf][r] = (k > q) ? -1e30f : v;
          }
        }
      } else {
        #pragma unroll
        for (int nf = 0; nf < 4; ++nf)
          #pragma unroll
          for (int r = 0; r < 4; ++r)
            s[nf][r] *= sc2;
      }

      // defer-max (T13, THR=8 in log2 units): wave-uniform check
      bool need = false;
      float lm[4];
      #pragma unroll
      for (int r = 0; r < 4; ++r) {
        lm[r] = fmaxf(fmaxf(s[0][r], s[1][r]), fmaxf(s[2][r], s[3][r]));
        need = need || (lm[r] > m_r[r] + 8.f);
      }
      if (__any((int)need)) {
        #pragma unroll
        for (int r = 0; r < 4; ++r) {
          float mx = lm[r];
          #pragma unroll
          for (int mk = 1; mk < 16; mk <<= 1) mx = fmaxf(mx, __shfl_xor(mx, mk));
          float mo = m_r[r];
          float mn = fmaxf(mo, mx);
          float alpha = exp2f(mo - mn);
          m_r[r] = mn;
          l_r[r] *= alpha;
          #pragma unroll
          for (int df = 0; df < 8; ++df) oacc[df][r] *= alpha;
        }
      }

      // P = exp2(s - m), row-sum (always)
      #pragma unroll
      for (int r = 0; r < 4; ++r) {
        float rs = 0.f;
        #pragma unroll
        for (int nf = 0; nf < 4; ++nf) {
          float p = exp2f(s[nf][r] - m_r[r]);
          s[nf][r] = p;
          rs += p;
        }
        #pragma unroll
        for (int mk = 1; mk < 16; mk <<= 1) rs += __shfl_xor(rs, mk);
        l_r[r] += rs;
      }

      // P -> LDS (per-wave region), then PV (setprio around MFMA cluster)
      #pragma unroll
      for (int nf = 0; nf < 4; ++nf)
        #pragma unroll
        for (int r = 0; r < 4; ++r)
          lP[w][(lg * 4 + r) * 72 + nf * 16 + lr] = __float2bfloat16(s[nf][r]);
      asm volatile("s_waitcnt lgkmcnt(0)" ::: "memory");

      #pragma unroll
      for (int ks2 = 0; ks2 < 2; ++ks2) {
        bf16x8 pa = *(const bf16x8*)&lP[w][lr * 72 + ks2 * 32 + lg * 8];
        __builtin_amdgcn_s_setprio(1);
        #pragma unroll
        for (int df = 0; df < 8; ++df) {
          int row = df * 16 + lr;
          bf16x8 vf = *(const bf16x8*)&lV[cur][row * 64 + ((ks2 * 4 + lg) ^ (row & 7)) * 8];
          oacc[df] = __builtin_amdgcn_mfma_f32_16x16x32_bf16(pa, vf, oacc[df], 0, 0, 0);
        }
        __builtin_amdgcn_s_setprio(0);
      }
      __syncthreads();                      // drains next-tile stage (vmcnt 0) + LDS
      cur ^= 1;
    }

    // normalize + write O[s][h*128+d]
    #pragma unroll
    for (int r = 0; r < 4; ++r) {
      float inv = 1.f / l_r[r];
      long q = q0 + w * 16 + lg * 4 + r;
      #pragma unroll
      for (int df = 0; df < 8; ++df)
        O[q * HID + h * HD + df * 16 + lr] = __float2bfloat16(oacc[df][r] * inv);
    }
    __syncthreads();                        // phase boundary: lK/lV reuse
  }
}

// ---------- launcher ----------
extern "C" void kernel_launch(void* const* d_in, const int* in_sizes, int n_in,
                              void* d_out, int out_size, void* d_ws, size_t ws_size,
                              hipStream_t stream)
{
  (void)in_sizes; (void)n_in; (void)out_size;
  const float* hidden = (const float*)d_in[0];
  const int*   pos    = (const int*)d_in[1];
  const float* wqkv_w = (const float*)d_in[2];
  const float* wqkv_b = (const float*)d_in[3];
  const float* wo_w   = (const float*)d_in[4];
  const float* wo_b   = (const float*)d_in[5];
  float* out = (float*)d_out;

  // ws layout (bytes). Phase 1: hid_bf | wqkv_bf | qkv_bf.
  // Phase 2+ reuses hid_bf region as Qr, wqkv_bf region as Kr/Vt/Obf/Wo_bf/tables.
  char* ws = (char*)d_ws;
  if (ws_size < 167772160UL) return;        // need 160 MB
  __hip_bfloat16* hid_bf  = (__hip_bfloat16*)(ws + 0);          // 16 MB, later Qr
  __hip_bfloat16* wqkv_bf = (__hip_bfloat16*)(ws + 16777216);   // 96 MB
  __hip_bfloat16* qr      = (__hip_bfloat16*)(ws + 0);
  __hip_bfloat16* kr      = (__hip_bfloat16*)(ws + 16777216);
  __hip_bfloat16* vt      = (__hip_bfloat16*)(ws + 33554432);
  __hip_bfloat16* obf     = (__hip_bfloat16*)(ws + 50331648);
  __hip_bfloat16* wo_bf   = (__hip_bfloat16*)(ws + 67108864);   // 32 MB
  float*          cos_t   = (float*)(ws + 100663296);
  float*          sin_t   = (float*)(ws + 100663296 + 524288);
  __hip_bfloat16* qkv_bf  = (__hip_bfloat16*)(ws + 117440512);  // 48 MB -> total 160 MB

  cvt_bf16_kernel<<<4096, 256, 0, stream>>>(hidden, hid_bf, 8388608L);
  cvt_bf16_kernel<<<8192, 256, 0, stream>>>(wqkv_w, wqkv_bf, 50331648L);
  gemm_bt_kernel<1><<<dim3(16, 96), 256, 0, stream>>>(hid_bf, wqkv_bf, wqkv_b, qkv_bf, 2048, 12288, 4096);
  // safe to overwrite wqkv region only after the QKV GEMM
  cvt_bf16_kernel<<<8192, 256, 0, stream>>>(wo_w, wo_bf, 16777216L);
  rope_table_kernel<<<2048, 64, 0, stream>>>(pos, cos_t, sin_t);
  rope_rearrange_kernel<<<dim3(32, 32), 256, 0, stream>>>(qkv_bf, cos_t, sin_t, qr, kr, vt);
  flash_attn_kernel<<<dim3(16, 32), 256, 0, stream>>>(qr, kr, vt, obf);
  gemm_bt_kernel<0><<<dim3(16, 32), 256, 0, stream>>>(obf, wo_bf, wo_b, out, 2048, 4096, 4096);
}